// Round 5
// baseline (167.538 us; speedup 1.0000x reference)
//
#include <hip/hip_runtime.h>

#define SEQ 2048
#define NH 16
#define HD 64
#define EMB 1024

typedef __attribute__((ext_vector_type(4))) float f32x4;
typedef __attribute__((ext_vector_type(16))) float f32x16;
typedef __attribute__((ext_vector_type(8))) __bf16 bf16x8;
typedef unsigned int u32x2 __attribute__((ext_vector_type(2)));
typedef unsigned int u32x4 __attribute__((ext_vector_type(4)));

__device__ inline unsigned short f2bf(float f){
  unsigned int u = __float_as_uint(f);
  return (unsigned short)((u + 0x7fffu + ((u >> 16) & 1u)) >> 16);
}
__device__ inline float bf2f(unsigned short h){ return __uint_as_float(((unsigned int)h) << 16); }

__device__ inline unsigned cvtpk(float lo, float hi){
  unsigned r;
  asm("v_cvt_pk_bf16_f32 %0, %1, %2" : "=v"(r) : "v"(lo), "v"(hi));
  return r;
}
__device__ inline u32x2 plswap(unsigned a, unsigned b){
  return __builtin_amdgcn_permlane32_swap(a, b, false, false);
}

// ---------------- x f32 -> bf16 ----------------
__global__ __launch_bounds__(256) void k_convert(const float* __restrict__ in,
                                                 unsigned short* __restrict__ out, int n8){
  int i = blockIdx.x * 256 + threadIdx.x;
  if (i >= n8) return;
  const float4* p = (const float4*)in + (size_t)i * 2;
  float4 a = p[0], b = p[1];
  uint4 r;
  r.x = f2bf(a.x) | ((unsigned)f2bf(a.y) << 16);
  r.y = f2bf(a.z) | ((unsigned)f2bf(a.w) << 16);
  r.z = f2bf(b.x) | ((unsigned)f2bf(b.y) << 16);
  r.w = f2bf(b.z) | ((unsigned)f2bf(b.w) << 16);
  ((uint4*)out)[i] = r;
}

// ------------- W [K][N] f32 -> Wt [N][K] bf16 (tile transpose) -------------
__global__ __launch_bounds__(256) void k_transpose_w(const float* __restrict__ Wq, const float* __restrict__ Wk,
                                                     const float* __restrict__ Wv, const float* __restrict__ Wo,
                                                     unsigned short* __restrict__ WtQKV,
                                                     unsigned short* __restrict__ WtO){
  int z = blockIdx.z;
  const float* W = (z == 0) ? Wq : (z == 1) ? Wk : (z == 2) ? Wv : Wo;
  unsigned short* out = (z < 3) ? (WtQKV + (size_t)z * EMB * EMB) : WtO;
  __shared__ float t[32][33];
  int n0 = blockIdx.x * 32, k0 = blockIdx.y * 32;
  int tx = threadIdx.x, ty = threadIdx.y;
  #pragma unroll
  for (int i = 0; i < 4; ++i)
    t[ty + i * 8][tx] = W[(size_t)(k0 + ty + i * 8) * EMB + n0 + tx];
  __syncthreads();
  #pragma unroll
  for (int i = 0; i < 4; ++i)
    out[(size_t)(n0 + ty + i * 8) * EMB + k0 + tx] = f2bf(t[tx][ty + i * 8]);
}

// ---------------- RoPE cos/sin table [S][32] ----------------
__global__ __launch_bounds__(256) void k_rope_table(float2* __restrict__ tb){
  int idx = blockIdx.x * 256 + threadIdx.x;   // 65536
  int s = idx >> 5, j = idx & 31;
  float invf = __expf(-(float)j * (9.210340371976184f / 32.0f));  // 10000^(-j/32)
  float ang = (float)s * invf;
  tb[idx] = make_float2(cosf(ang), sinf(ang));
}

// ---------------- GEMM: C[M=4096][N] = A[M][1024] * Bt[N][1024]^T ----------------
// MODE 0: N=3072, scatter to Q/K/V [B*H][S][D] bf16 (Q pre-scaled by 0.125).
// MODE 1: N=1024, f32 out.
template<int MODE>
__global__ __launch_bounds__(256, 2) void k_gemm(const unsigned short* __restrict__ A,
                                                 const unsigned short* __restrict__ Bt,
                                                 unsigned short* __restrict__ Qb,
                                                 unsigned short* __restrict__ Kb,
                                                 unsigned short* __restrict__ Vb,
                                                 float* __restrict__ FO){
  const int Kd = 1024;
  int m0 = blockIdx.x * 128, n0 = blockIdx.y * 128;
  int tid = threadIdx.x;
  int w = tid >> 6, lane = tid & 63;
  int wm = w >> 1, wn = w & 1;
  int g = lane >> 4, lr = lane & 15;
  __shared__ unsigned short Ash[128 * 64];
  __shared__ unsigned short Bsh[128 * 64];
  f32x4 acc[4][4] = {};
  int r_ = tid >> 3, c_ = tid & 7;
  int rm = r_ & 7;                // (row & 7) for the staged rows
  int cc = c_ ^ rm;               // pre-swizzled source chunk (rule #21)
  for (int kt = 0; kt < Kd / 64; ++kt){
    int kb = kt * 64;
    #pragma unroll
    for (int it = 0; it < 4; ++it){
      int row = it * 32 + r_;
      __builtin_amdgcn_global_load_lds(
        (const __attribute__((address_space(1))) void*)(A + (size_t)(m0 + row) * Kd + kb + cc * 8),
        (__attribute__((address_space(3))) void*)(Ash + it * 2048 + tid * 8), 16, 0, 0);
      __builtin_amdgcn_global_load_lds(
        (const __attribute__((address_space(1))) void*)(Bt + (size_t)(n0 + row) * Kd + kb + cc * 8),
        (__attribute__((address_space(3))) void*)(Bsh + it * 2048 + tid * 8), 16, 0, 0);
    }
    __syncthreads();
    #pragma unroll
    for (int kk = 0; kk < 2; ++kk){
      bf16x8 af[4], bfr[4];
      #pragma unroll
      for (int i = 0; i < 4; ++i){
        int ra = wm * 64 + i * 16 + lr;
        af[i]  = *(const bf16x8*)(Ash + ra * 64 + (((kk * 4 + g) ^ (ra & 7)) * 8));
        int rb = wn * 64 + i * 16 + lr;
        bfr[i] = *(const bf16x8*)(Bsh + rb * 64 + (((kk * 4 + g) ^ (rb & 7)) * 8));
      }
      #pragma unroll
      for (int mi = 0; mi < 4; ++mi)
        #pragma unroll
        for (int ni = 0; ni < 4; ++ni)
          acc[mi][ni] = __builtin_amdgcn_mfma_f32_16x16x32_bf16(af[mi], bfr[ni], acc[mi][ni], 0, 0, 0);
    }
    __syncthreads();
  }
  #pragma unroll
  for (int mi = 0; mi < 4; ++mi){
    #pragma unroll
    for (int ni = 0; ni < 4; ++ni){
      int col = n0 + wn * 64 + ni * 16 + lr;
      #pragma unroll
      for (int r = 0; r < 4; ++r){
        int mrow = m0 + wm * 64 + mi * 16 + 4 * g + r;   // = b*S + s
        float v = acc[mi][ni][r];
        if constexpr (MODE == 0){
          int mat = col >> 10, e = col & 1023;
          int h = e >> 6, d = e & 63;
          int bb = mrow >> 11, s = mrow & 2047;
          size_t off = ((size_t)((bb * NH + h) * SEQ + s)) * HD + d;
          if (mat == 0) v *= 0.125f;   // fold 1/sqrt(D) into Q
          unsigned short* dst = (mat == 0) ? Qb : (mat == 1) ? Kb : Vb;
          dst[off] = f2bf(v);
        } else {
          FO[(size_t)mrow * EMB + col] = v;
        }
      }
    }
  }
}

// ---------------- RoPE in-place on Q and K ([B*H][S][64] bf16) ----------------
__global__ __launch_bounds__(256) void k_rope(unsigned short* __restrict__ Qb,
                                              unsigned short* __restrict__ Kb,
                                              const float2* __restrict__ tb){
  int rid = blockIdx.x * 8 + (threadIdx.x >> 5);   // 0..131071
  int j = threadIdx.x & 31;
  int which = rid >> 16;                            // 0=Q rows, 1=K rows (65536 each)
  int rem = rid & 65535;                            // = bh*2048 + s
  int s = rem & 2047;
  unsigned short* base = (which ? Kb : Qb) + (size_t)rem * 64;
  unsigned int eo = *(const unsigned int*)(base + 2 * j);   // elems 2j, 2j+1
  float ej = bf2f((unsigned short)(eo & 0xffff));
  float oj = bf2f((unsigned short)(eo >> 16));
  float a_e = __shfl(ej, (j >> 1), 32);
  float a_o = __shfl(oj, (j >> 1), 32);
  float h_e = __shfl(ej, 16 + (j >> 1), 32);
  float h_o = __shfl(oj, 16 + (j >> 1), 32);
  float aval = (j & 1) ? a_o : a_e;    // q[j]
  float hval = (j & 1) ? h_o : h_e;    // q[32+j]
  float2 cs = tb[s * 32 + j];
  base[j]      = f2bf(aval * cs.x - oj * cs.y);   // q[j]c - q[2j+1]s
  base[32 + j] = f2bf(hval * cs.x + ej * cs.y);   // q[32+j]c + q[2j]s
}

// ---------------- V [bh][S][64] -> Vt [bh][64][S] ----------------
__global__ __launch_bounds__(256) void k_transpose_v(const unsigned short* __restrict__ V,
                                                     unsigned short* __restrict__ Vt){
  int bh = blockIdx.z;
  const unsigned short* src = V + (size_t)bh * SEQ * HD;
  unsigned short* dst = Vt + (size_t)bh * HD * SEQ;
  __shared__ unsigned short t[32][33];
  int s0 = blockIdx.x * 32, d0 = blockIdx.y * 32;
  int tx = threadIdx.x, ty = threadIdx.y;
  #pragma unroll
  for (int i = 0; i < 4; ++i)
    t[ty + i * 8][tx] = src[(size_t)(s0 + ty + i * 8) * HD + d0 + tx];
  __syncthreads();
  #pragma unroll
  for (int i = 0; i < 4; ++i)
    dst[(size_t)(d0 + ty + i * 8) * SEQ + s0 + tx] = t[tx][ty + i * 8];
}

// ---------------- causal flash attention, swapped-QK^T in-register softmax ----------------
// one wave (64 thr) per block; wave owns 32 q rows; KVBLK=32; 32x32x16 MFMA.
// K AND V both prefetched one tile ahead (unconditional clamped addresses, register rotation).
// Q pre-scaled by 1/sqrt(D) in the QKV GEMM epilogue.
__global__ __launch_bounds__(64, 2) void k_attn(const unsigned short* __restrict__ Qb,
                                                const unsigned short* __restrict__ Kb,
                                                const unsigned short* __restrict__ Vt,
                                                unsigned short* __restrict__ AO){
  int b0 = blockIdx.x;               // 2048 blocks
  int seq = b0 >> 3;
  int bh = (b0 & 7) + 8 * (seq >> 6);   // group 4 bh per XCD slot -> K/V fits per-XCD L2
  int j = 63 - (seq & 63);              // long tasks first
  int q0 = j * 32;
  int l = threadIdx.x;
  int lr = l & 31, h = l >> 5;
  const unsigned short* Qp = Qb + (size_t)bh * SEQ * HD;
  const unsigned short* Kp = Kb + (size_t)bh * SEQ * HD;
  const unsigned short* Vp = Vt + (size_t)bh * HD * SEQ;

  // Q as B-operand: lane l holds Q[q0 + (l&31)][d = d0*16 + (l>>5)*8 + j]
  bf16x8 qf[4];
  #pragma unroll
  for (int d0 = 0; d0 < 4; ++d0)
    qf[d0] = *(const bf16x8*)(Qp + (size_t)(q0 + lr) * HD + d0 * 16 + h * 8);

  int nt = j + 1;

  // prologue: K(0), V(0) resident
  bf16x8 kf[4];
  #pragma unroll
  for (int d0 = 0; d0 < 4; ++d0)
    kf[d0] = *(const bf16x8*)(Kp + (size_t)lr * HD + d0 * 16 + h * 8);
  bf16x8 vf[2][2];
  #pragma unroll
  for (int dt = 0; dt < 2; ++dt)
    #pragma unroll
    for (int s = 0; s < 2; ++s)
      vf[dt][s] = *(const bf16x8*)(Vp + (size_t)(dt * 32 + lr) * SEQ + s * 16 + h * 8);

  f32x16 ot0 = {}, ot1 = {};           // O^T accum: row=d-local, col=q
  float mS = -1e30f, lS = 0.f;

  for (int t = 0; t < nt; ++t){
    int kv0 = t * 32;
    // prefetch K(t+1), V(t+1) (clamped, unconditional) — consumed NEXT iteration
    int nxt = (kv0 + 32 > q0) ? q0 : kv0 + 32;
    bf16x8 kn[4];
    #pragma unroll
    for (int d0 = 0; d0 < 4; ++d0)
      kn[d0] = *(const bf16x8*)(Kp + (size_t)(nxt + lr) * HD + d0 * 16 + h * 8);
    bf16x8 vn[2][2];
    #pragma unroll
    for (int dt = 0; dt < 2; ++dt)
      #pragma unroll
      for (int s = 0; s < 2; ++s)
        vn[dt][s] = *(const bf16x8*)(Vp + (size_t)(dt * 32 + lr) * SEQ + nxt + s * 16 + h * 8);
    // S^T = K * Q^T : lane holds 16 k-values of row q = lane&31
    __builtin_amdgcn_s_setprio(1);
    f32x16 st = {};
    #pragma unroll
    for (int d0 = 0; d0 < 4; ++d0)
      st = __builtin_amdgcn_mfma_f32_32x32x16_bf16(kf[d0], qf[d0], st, 0, 0, 0);
    __builtin_amdgcn_s_setprio(0);
    if (t == nt - 1){
      #pragma unroll
      for (int r = 0; r < 16; ++r){
        int kkl = (r & 3) + 8 * (r >> 2) + 4 * h;
        if (kkl > lr) st[r] = -3.0e38f;
      }
    }
    // row max: in-lane tree + half-exchange
    float mx[8];
    #pragma unroll
    for (int r = 0; r < 8; ++r) mx[r] = fmaxf(st[r], st[r + 8]);
    #pragma unroll
    for (int r = 0; r < 4; ++r) mx[r] = fmaxf(mx[r], mx[r + 4]);
    float m01 = fmaxf(fmaxf(mx[0], mx[1]), fmaxf(mx[2], mx[3]));
    u32x2 mm = plswap(__float_as_uint(m01), __float_as_uint(m01));
    float tm = fmaxf(__uint_as_float(mm.x), __uint_as_float(mm.y));
    // defer-max rescale (THR = 1.0 => P bounded by e)
    if (__any(tm > mS + 1.0f)){
      float mn = fmaxf(mS, tm);
      float al = __expf(mS - mn);
      mS = mn;
      lS *= al;
      #pragma unroll
      for (int r = 0; r < 16; ++r){ ot0[r] *= al; ot1[r] *= al; }
    }
    // P = exp(S - m), in place
    #pragma unroll
    for (int r = 0; r < 16; ++r)
      st[r] = __expf(st[r] - mS);
    // row sum
    float sm[8];
    #pragma unroll
    for (int r = 0; r < 8; ++r) sm[r] = st[r] + st[r + 8];
    #pragma unroll
    for (int r = 0; r < 4; ++r) sm[r] = sm[r] + sm[r + 4];
    float ps = (sm[0] + sm[1]) + (sm[2] + sm[3]);
    u32x2 ss = plswap(__float_as_uint(ps), __float_as_uint(ps));
    lS += __uint_as_float(ss.x) + __uint_as_float(ss.y);
    // pack P -> bf16 B-frags via cvt_pk + permlane32_swap (T12), register-only
    bf16x8 pf[2];
    #pragma unroll
    for (int s = 0; s < 2; ++s){
      unsigned c0 = cvtpk(st[8 * s + 0], st[8 * s + 1]);
      unsigned c1 = cvtpk(st[8 * s + 2], st[8 * s + 3]);
      unsigned c2 = cvtpk(st[8 * s + 4], st[8 * s + 5]);
      unsigned c3 = cvtpk(st[8 * s + 6], st[8 * s + 7]);
      u32x2 r02 = plswap(c0, c2);
      u32x2 r13 = plswap(c1, c3);
      u32x4 uw;
      uw.x = r02.x; uw.y = r13.x; uw.z = r02.y; uw.w = r13.y;
      pf[s] = __builtin_bit_cast(bf16x8, uw);
    }
    // O^T += V^T * P^T
    __builtin_amdgcn_s_setprio(1);
    #pragma unroll
    for (int s = 0; s < 2; ++s){
      ot0 = __builtin_amdgcn_mfma_f32_32x32x16_bf16(vf[0][s], pf[s], ot0, 0, 0, 0);
      ot1 = __builtin_amdgcn_mfma_f32_32x32x16_bf16(vf[1][s], pf[s], ot1, 0, 0, 0);
    }
    __builtin_amdgcn_s_setprio(0);
    // rotate prefetch registers (static indices only)
    #pragma unroll
    for (int d0 = 0; d0 < 4; ++d0) kf[d0] = kn[d0];
    #pragma unroll
    for (int dt = 0; dt < 2; ++dt)
      #pragma unroll
      for (int s = 0; s < 2; ++s) vf[dt][s] = vn[dt][s];
  }
  // epilogue: lane l holds O^T[d][q=lane&31]; d = dt*32 + 8*rq + 4*h + (0..3)
  int b = bh >> 4, hh = bh & 15;
  float inv = 1.0f / lS;
  unsigned short* outp = AO + ((size_t)(b * SEQ + q0 + lr)) * EMB + hh * HD;
  #pragma unroll
  for (int dt = 0; dt < 2; ++dt){
    #pragma unroll
    for (int rq = 0; rq < 4; ++rq){
      float v0 = (dt ? ot1 : ot0)[rq * 4 + 0] * inv;
      float v1 = (dt ? ot1 : ot0)[rq * 4 + 1] * inv;
      float v2 = (dt ? ot1 : ot0)[rq * 4 + 2] * inv;
      float v3 = (dt ? ot1 : ot0)[rq * 4 + 3] * inv;
      uint2 wv;
      wv.x = cvtpk(v0, v1);
      wv.y = cvtpk(v2, v3);
      int d0 = dt * 32 + 8 * rq + 4 * h;
      *(uint2*)(outp + d0) = wv;
    }
  }
}

extern "C" void kernel_launch(void* const* d_in, const int* in_sizes, int n_in,
                              void* d_out, int out_size, void* d_ws, size_t ws_size,
                              hipStream_t stream){
  const float* x  = (const float*)d_in[0];
  const float* Wq = (const float*)d_in[2];
  const float* Wk = (const float*)d_in[3];
  const float* Wv = (const float*)d_in[4];
  const float* Wo = (const float*)d_in[5];
  float* out = (float*)d_out;

  char* ws = (char*)d_ws;
  size_t off = 0;
  auto alloc = [&](size_t bytes){ void* p = ws + off; off += (bytes + 255) & ~(size_t)255; return p; };
  unsigned short* xb    = (unsigned short*)alloc((size_t)4096 * 1024 * 2);
  unsigned short* wtqkv = (unsigned short*)alloc((size_t)3072 * 1024 * 2);
  unsigned short* wto   = (unsigned short*)alloc((size_t)1024 * 1024 * 2);
  unsigned short* qb    = (unsigned short*)alloc((size_t)4096 * 1024 * 2);
  unsigned short* kb    = (unsigned short*)alloc((size_t)4096 * 1024 * 2);
  unsigned short* vb    = (unsigned short*)alloc((size_t)4096 * 1024 * 2);
  float2*         tb    = (float2*)alloc((size_t)2048 * 32 * 8);
  unsigned short* vt = xb;   // xb dead after QKV GEMM
  unsigned short* ao = vb;   // vb dead after V transpose

  k_convert<<<dim3(2048), dim3(256), 0, stream>>>(x, xb, 524288);
  k_transpose_w<<<dim3(32, 32, 4), dim3(32, 8), 0, stream>>>(Wq, Wk, Wv, Wo, wtqkv, wto);
  k_rope_table<<<dim3(256), dim3(256), 0, stream>>>(tb);
  k_gemm<0><<<dim3(32, 24), dim3(256), 0, stream>>>(xb, wtqkv, qb, kb, vb, nullptr);
  k_rope<<<dim3(16384), dim3(256), 0, stream>>>(qb, kb, tb);
  k_transpose_v<<<dim3(64, 2, 32), dim3(32, 8), 0, stream>>>(vb, vt);
  k_attn<<<dim3(2048), dim3(64), 0, stream>>>(qb, kb, vt, ao);
  k_gemm<1><<<dim3(32, 8), dim3(256), 0, stream>>>(ao, wto, nullptr, nullptr, nullptr, out);
}

// Round 6
// 124.615 us; speedup vs baseline: 1.3444x; 1.3444x over previous
//
#include <hip/hip_runtime.h>

#define SEQ 2048
#define NH 16
#define HD 64
#define EMB 1024

typedef __attribute__((ext_vector_type(4))) float f32x4;
typedef __attribute__((ext_vector_type(16))) float f32x16;
typedef __attribute__((ext_vector_type(8))) __bf16 bf16x8;
typedef unsigned int u32x2 __attribute__((ext_vector_type(2)));
typedef unsigned int u32x4 __attribute__((ext_vector_type(4)));

__device__ inline unsigned short f2bf(float f){
  unsigned int u = __float_as_uint(f);
  return (unsigned short)((u + 0x7fffu + ((u >> 16) & 1u)) >> 16);
}
__device__ inline float bf2f(unsigned short h){ return __uint_as_float(((unsigned int)h) << 16); }

__device__ inline unsigned cvtpk(float lo, float hi){
  unsigned r;
  asm("v_cvt_pk_bf16_f32 %0, %1, %2" : "=v"(r) : "v"(lo), "v"(hi));
  return r;
}
__device__ inline u32x2 plswap(unsigned a, unsigned b){
  return __builtin_amdgcn_permlane32_swap(a, b, false, false);
}

// ---------------- x f32 -> bf16 ----------------
__global__ __launch_bounds__(256) void k_convert(const float* __restrict__ in,
                                                 unsigned short* __restrict__ out, int n8){
  int i = blockIdx.x * 256 + threadIdx.x;
  if (i >= n8) return;
  const float4* p = (const float4*)in + (size_t)i * 2;
  float4 a = p[0], b = p[1];
  uint4 r;
  r.x = f2bf(a.x) | ((unsigned)f2bf(a.y) << 16);
  r.y = f2bf(a.z) | ((unsigned)f2bf(a.w) << 16);
  r.z = f2bf(b.x) | ((unsigned)f2bf(b.y) << 16);
  r.w = f2bf(b.z) | ((unsigned)f2bf(b.w) << 16);
  ((uint4*)out)[i] = r;
}

// ------------- W [K][N] f32 -> Wt [N][K] bf16 (tile transpose) -------------
__global__ __launch_bounds__(256) void k_transpose_w(const float* __restrict__ Wq, const float* __restrict__ Wk,
                                                     const float* __restrict__ Wv, const float* __restrict__ Wo,
                                                     unsigned short* __restrict__ WtQKV,
                                                     unsigned short* __restrict__ WtO){
  int z = blockIdx.z;
  const float* W = (z == 0) ? Wq : (z == 1) ? Wk : (z == 2) ? Wv : Wo;
  unsigned short* out = (z < 3) ? (WtQKV + (size_t)z * EMB * EMB) : WtO;
  __shared__ float t[32][33];
  int n0 = blockIdx.x * 32, k0 = blockIdx.y * 32;
  int tx = threadIdx.x, ty = threadIdx.y;
  #pragma unroll
  for (int i = 0; i < 4; ++i)
    t[ty + i * 8][tx] = W[(size_t)(k0 + ty + i * 8) * EMB + n0 + tx];
  __syncthreads();
  #pragma unroll
  for (int i = 0; i < 4; ++i)
    out[(size_t)(n0 + ty + i * 8) * EMB + k0 + tx] = f2bf(t[tx][ty + i * 8]);
}

// ---------------- RoPE cos/sin table [S][32] ----------------
__global__ __launch_bounds__(256) void k_rope_table(float2* __restrict__ tb){
  int idx = blockIdx.x * 256 + threadIdx.x;   // 65536
  int s = idx >> 5, j = idx & 31;
  float invf = __expf(-(float)j * (9.210340371976184f / 32.0f));  // 10000^(-j/32)
  float ang = (float)s * invf;
  tb[idx] = make_float2(cosf(ang), sinf(ang));
}

// ---------------- GEMM: C[M=4096][N] = A[M][1024] * Bt[N][1024]^T ----------------
// MODE 0: N=3072, scatter to Q/K/V [B*H][S][D] bf16 (Q pre-scaled by 0.125).
// MODE 1: N=1024, f32 out.
template<int MODE>
__global__ __launch_bounds__(256, 2) void k_gemm(const unsigned short* __restrict__ A,
                                                 const unsigned short* __restrict__ Bt,
                                                 unsigned short* __restrict__ Qb,
                                                 unsigned short* __restrict__ Kb,
                                                 unsigned short* __restrict__ Vb,
                                                 float* __restrict__ FO){
  const int Kd = 1024;
  int m0 = blockIdx.x * 128, n0 = blockIdx.y * 128;
  int tid = threadIdx.x;
  int w = tid >> 6, lane = tid & 63;
  int wm = w >> 1, wn = w & 1;
  int g = lane >> 4, lr = lane & 15;
  __shared__ unsigned short Ash[128 * 64];
  __shared__ unsigned short Bsh[128 * 64];
  f32x4 acc[4][4] = {};
  int r_ = tid >> 3, c_ = tid & 7;
  int rm = r_ & 7;                // (row & 7) for the staged rows
  int cc = c_ ^ rm;               // pre-swizzled source chunk (rule #21)
  for (int kt = 0; kt < Kd / 64; ++kt){
    int kb = kt * 64;
    #pragma unroll
    for (int it = 0; it < 4; ++it){
      int row = it * 32 + r_;
      __builtin_amdgcn_global_load_lds(
        (const __attribute__((address_space(1))) void*)(A + (size_t)(m0 + row) * Kd + kb + cc * 8),
        (__attribute__((address_space(3))) void*)(Ash + it * 2048 + tid * 8), 16, 0, 0);
      __builtin_amdgcn_global_load_lds(
        (const __attribute__((address_space(1))) void*)(Bt + (size_t)(n0 + row) * Kd + kb + cc * 8),
        (__attribute__((address_space(3))) void*)(Bsh + it * 2048 + tid * 8), 16, 0, 0);
    }
    __syncthreads();
    #pragma unroll
    for (int kk = 0; kk < 2; ++kk){
      bf16x8 af[4], bfr[4];
      #pragma unroll
      for (int i = 0; i < 4; ++i){
        int ra = wm * 64 + i * 16 + lr;
        af[i]  = *(const bf16x8*)(Ash + ra * 64 + (((kk * 4 + g) ^ (ra & 7)) * 8));
        int rb = wn * 64 + i * 16 + lr;
        bfr[i] = *(const bf16x8*)(Bsh + rb * 64 + (((kk * 4 + g) ^ (rb & 7)) * 8));
      }
      #pragma unroll
      for (int mi = 0; mi < 4; ++mi)
        #pragma unroll
        for (int ni = 0; ni < 4; ++ni)
          acc[mi][ni] = __builtin_amdgcn_mfma_f32_16x16x32_bf16(af[mi], bfr[ni], acc[mi][ni], 0, 0, 0);
    }
    __syncthreads();
  }
  #pragma unroll
  for (int mi = 0; mi < 4; ++mi){
    #pragma unroll
    for (int ni = 0; ni < 4; ++ni){
      int col = n0 + wn * 64 + ni * 16 + lr;
      #pragma unroll
      for (int r = 0; r < 4; ++r){
        int mrow = m0 + wm * 64 + mi * 16 + 4 * g + r;   // = b*S + s
        float v = acc[mi][ni][r];
        if constexpr (MODE == 0){
          int mat = col >> 10, e = col & 1023;
          int h = e >> 6, d = e & 63;
          int bb = mrow >> 11, s = mrow & 2047;
          size_t off = ((size_t)((bb * NH + h) * SEQ + s)) * HD + d;
          if (mat == 0) v *= 0.125f;   // fold 1/sqrt(D) into Q
          unsigned short* dst = (mat == 0) ? Qb : (mat == 1) ? Kb : Vb;
          dst[off] = f2bf(v);
        } else {
          FO[(size_t)mrow * EMB + col] = v;
        }
      }
    }
  }
}

// ---- RoPE + repack Q/K rows into MFMA-fragment-major layout ----
// Fragment chunk (bh, tile, d0, lane l) = 8 bf16: row = tile*32+(l&31),
// elems d = d0*16 + (l>>5)*8 + 0..7, rope applied. 16B/lane coalesced stores.
__global__ __launch_bounds__(64) void k_rope_frag(const unsigned short* __restrict__ Qin,
                                                  const unsigned short* __restrict__ Kin,
                                                  unsigned short* __restrict__ Qf,
                                                  unsigned short* __restrict__ Kf,
                                                  const float2* __restrict__ tb){
  int t = blockIdx.x, bh = blockIdx.y, z = blockIdx.z;
  const unsigned short* src = (z ? Kin : Qin) + ((size_t)bh * SEQ + t * 32) * HD;
  unsigned short* dst = z ? Kf : Qf;
  __shared__ __align__(16) unsigned char lds[32 * 160];
  int l = threadIdx.x, lr = l & 31, h = l >> 5;
  // stage 32x64 bf16 tile (contiguous 4KB) into padded LDS rows (160B stride)
  #pragma unroll
  for (int p = 0; p < 4; ++p){
    int i = p * 64 + l;
    uint4 g = ((const uint4*)src)[i];
    *(uint4*)(lds + (i >> 3) * 160 + (i & 7) * 16) = g;
  }
  __syncthreads();
  int srow = t * 32 + lr;
  #pragma unroll
  for (int d0 = 0; d0 < 4; ++d0){
    int j0 = (d0 & 1) * 16 + h * 8;
    bf16x8 own = *(const bf16x8*)(lds + lr * 160 + d0 * 32 + h * 16);
    bf16x8 plo = *(const bf16x8*)(lds + lr * 160 + (d0 & 1) * 64 + h * 32);
    bf16x8 phi = *(const bf16x8*)(lds + lr * 160 + (d0 & 1) * 64 + h * 32 + 16);
    // d<32: partner = x[2d+1] (odd elems); d>=32: partner = x[2(d-32)] (even elems)
    bf16x8 part = (d0 < 2)
      ? __builtin_shufflevector(plo, phi, 1, 3, 5, 7, 9, 11, 13, 15)
      : __builtin_shufflevector(plo, phi, 0, 2, 4, 6, 8, 10, 12, 14);
    const float4* cp = (const float4*)(tb + (size_t)srow * 32 + j0);
    float4 c0 = cp[0], c1 = cp[1], c2 = cp[2], c3 = cp[3];
    float co[8] = {c0.x, c0.z, c1.x, c1.z, c2.x, c2.z, c3.x, c3.z};
    float si[8] = {c0.y, c0.w, c1.y, c1.w, c2.y, c2.w, c3.y, c3.w};
    float sg = (d0 < 2) ? -1.0f : 1.0f;
    unsigned w[4];
    #pragma unroll
    for (int i2 = 0; i2 < 4; ++i2){
      float e0 = (float)own[2 * i2]     * co[2 * i2]     + sg * (float)part[2 * i2]     * si[2 * i2];
      float e1 = (float)own[2 * i2 + 1] * co[2 * i2 + 1] + sg * (float)part[2 * i2 + 1] * si[2 * i2 + 1];
      w[i2] = (unsigned)f2bf(e0) | ((unsigned)f2bf(e1) << 16);
    }
    uint4 o; o.x = w[0]; o.y = w[1]; o.z = w[2]; o.w = w[3];
    ((uint4*)dst)[((size_t)(bh * 64 + t) * 4 + d0) * 64 + l] = o;
  }
}

// ---- V -> V^T fragment-major: chunk (bh,tile,dt*2+s2,lane l) = 8 bf16:
// elem e = V[bh][tile*32 + s2*16 + (l>>5)*8 + e][dt*32 + (l&31)] ----
__global__ __launch_bounds__(64) void k_vfrag(const unsigned short* __restrict__ V,
                                              unsigned short* __restrict__ Vf){
  int t = blockIdx.x, bh = blockIdx.y;
  const unsigned short* src = V + ((size_t)bh * SEQ + t * 32) * HD;
  __shared__ __align__(16) unsigned char lds[32 * 160];
  int l = threadIdx.x, lr = l & 31, h = l >> 5;
  #pragma unroll
  for (int p = 0; p < 4; ++p){
    int i = p * 64 + l;
    uint4 g = ((const uint4*)src)[i];
    *(uint4*)(lds + (i >> 3) * 160 + (i & 7) * 16) = g;
  }
  __syncthreads();
  #pragma unroll
  for (int dt = 0; dt < 2; ++dt){
    #pragma unroll
    for (int s2 = 0; s2 < 2; ++s2){
      unsigned w[4];
      #pragma unroll
      for (int i2 = 0; i2 < 4; ++i2){
        unsigned a = *(const unsigned short*)(lds + (s2 * 16 + h * 8 + 2 * i2) * 160 + (dt * 32 + lr) * 2);
        unsigned b = *(const unsigned short*)(lds + (s2 * 16 + h * 8 + 2 * i2 + 1) * 160 + (dt * 32 + lr) * 2);
        w[i2] = a | (b << 16);
      }
      uint4 o; o.x = w[0]; o.y = w[1]; o.z = w[2]; o.w = w[3];
      ((uint4*)Vf)[((size_t)(bh * 64 + t) * 4 + dt * 2 + s2) * 64 + l] = o;
    }
  }
}

// ---------------- causal flash attention, swapped-QK^T in-register softmax ----------------
// one wave per block; 32 q rows; KVBLK=32; 32x32x16 MFMA; fragment-major coalesced loads.
// K and V prefetched one tile ahead. Q pre-scaled by 1/sqrt(D).
__global__ __launch_bounds__(64, 2) void k_attn(const unsigned short* __restrict__ Qf,
                                                const unsigned short* __restrict__ Kf,
                                                const unsigned short* __restrict__ Vf,
                                                unsigned short* __restrict__ AO){
  int b0 = blockIdx.x;               // 2048 blocks
  int seq = b0 >> 3;
  int bh = (b0 & 7) + 8 * (seq >> 6);   // group 4 bh per XCD slot -> K/V fits per-XCD L2
  int j = 63 - (seq & 63);              // long tasks first
  int q0 = j * 32;
  int l = threadIdx.x;
  int lr = l & 31, h = l >> 5;
  const unsigned short* Qp = Qf + ((size_t)(bh * 64 + j) * 4) * 512;   // slot stride 512 u16
  const unsigned short* Kp = Kf + (size_t)bh * 64 * 4 * 512;
  const unsigned short* Vp = Vf + (size_t)bh * 64 * 4 * 512;

  bf16x8 qf[4];
  #pragma unroll
  for (int d0 = 0; d0 < 4; ++d0)
    qf[d0] = *(const bf16x8*)(Qp + d0 * 512 + l * 8);

  int nt = j + 1;

  // prologue: K(0), V(0) resident
  bf16x8 kf[4];
  #pragma unroll
  for (int d0 = 0; d0 < 4; ++d0)
    kf[d0] = *(const bf16x8*)(Kp + d0 * 512 + l * 8);
  bf16x8 vf[2][2];
  #pragma unroll
  for (int dt = 0; dt < 2; ++dt)
    #pragma unroll
    for (int s = 0; s < 2; ++s)
      vf[dt][s] = *(const bf16x8*)(Vp + (dt * 2 + s) * 512 + l * 8);

  f32x16 ot0 = {}, ot1 = {};           // O^T accum: row=d-local, col=q
  float mS = -1e30f, lS = 0.f;

  for (int t = 0; t < nt; ++t){
    // prefetch K(t+1), V(t+1) (clamped, unconditional) — consumed NEXT iteration
    int tn = (t + 1 > j) ? j : t + 1;
    const unsigned short* Kn = Kp + (size_t)tn * 4 * 512;
    const unsigned short* Vn = Vp + (size_t)tn * 4 * 512;
    bf16x8 kn[4];
    #pragma unroll
    for (int d0 = 0; d0 < 4; ++d0)
      kn[d0] = *(const bf16x8*)(Kn + d0 * 512 + l * 8);
    bf16x8 vn[2][2];
    #pragma unroll
    for (int dt = 0; dt < 2; ++dt)
      #pragma unroll
      for (int s = 0; s < 2; ++s)
        vn[dt][s] = *(const bf16x8*)(Vn + (dt * 2 + s) * 512 + l * 8);
    // S^T = K * Q^T : lane holds 16 k-values of row q = lane&31
    __builtin_amdgcn_s_setprio(1);
    f32x16 st = {};
    #pragma unroll
    for (int d0 = 0; d0 < 4; ++d0)
      st = __builtin_amdgcn_mfma_f32_32x32x16_bf16(kf[d0], qf[d0], st, 0, 0, 0);
    __builtin_amdgcn_s_setprio(0);
    if (t == nt - 1){
      #pragma unroll
      for (int r = 0; r < 16; ++r){
        int kkl = (r & 3) + 8 * (r >> 2) + 4 * h;
        if (kkl > lr) st[r] = -3.0e38f;
      }
    }
    // row max: in-lane tree + half-exchange
    float mx[8];
    #pragma unroll
    for (int r = 0; r < 8; ++r) mx[r] = fmaxf(st[r], st[r + 8]);
    #pragma unroll
    for (int r = 0; r < 4; ++r) mx[r] = fmaxf(mx[r], mx[r + 4]);
    float m01 = fmaxf(fmaxf(mx[0], mx[1]), fmaxf(mx[2], mx[3]));
    u32x2 mm = plswap(__float_as_uint(m01), __float_as_uint(m01));
    float tm = fmaxf(__uint_as_float(mm.x), __uint_as_float(mm.y));
    // defer-max rescale (THR = 1.0 => P bounded by e)
    if (__any(tm > mS + 1.0f)){
      float mn = fmaxf(mS, tm);
      float al = __expf(mS - mn);
      mS = mn;
      lS *= al;
      #pragma unroll
      for (int r = 0; r < 16; ++r){ ot0[r] *= al; ot1[r] *= al; }
    }
    // P = exp(S - m), in place
    #pragma unroll
    for (int r = 0; r < 16; ++r)
      st[r] = __expf(st[r] - mS);
    // row sum
    float sm[8];
    #pragma unroll
    for (int r = 0; r < 8; ++r) sm[r] = st[r] + st[r + 8];
    #pragma unroll
    for (int r = 0; r < 4; ++r) sm[r] = sm[r] + sm[r + 4];
    float ps = (sm[0] + sm[1]) + (sm[2] + sm[3]);
    u32x2 ss = plswap(__float_as_uint(ps), __float_as_uint(ps));
    lS += __uint_as_float(ss.x) + __uint_as_float(ss.y);
    // pack P -> bf16 B-frags via cvt_pk + permlane32_swap (T12), register-only
    bf16x8 pf[2];
    #pragma unroll
    for (int s = 0; s < 2; ++s){
      unsigned c0 = cvtpk(st[8 * s + 0], st[8 * s + 1]);
      unsigned c1 = cvtpk(st[8 * s + 2], st[8 * s + 3]);
      unsigned c2 = cvtpk(st[8 * s + 4], st[8 * s + 5]);
      unsigned c3 = cvtpk(st[8 * s + 6], st[8 * s + 7]);
      u32x2 r02 = plswap(c0, c2);
      u32x2 r13 = plswap(c1, c3);
      u32x4 uw;
      uw.x = r02.x; uw.y = r13.x; uw.z = r02.y; uw.w = r13.y;
      pf[s] = __builtin_bit_cast(bf16x8, uw);
    }
    // O^T += V^T * P^T
    __builtin_amdgcn_s_setprio(1);
    #pragma unroll
    for (int s = 0; s < 2; ++s){
      ot0 = __builtin_amdgcn_mfma_f32_32x32x16_bf16(vf[0][s], pf[s], ot0, 0, 0, 0);
      ot1 = __builtin_amdgcn_mfma_f32_32x32x16_bf16(vf[1][s], pf[s], ot1, 0, 0, 0);
    }
    __builtin_amdgcn_s_setprio(0);
    // rotate prefetch registers (static indices only)
    #pragma unroll
    for (int d0 = 0; d0 < 4; ++d0) kf[d0] = kn[d0];
    #pragma unroll
    for (int dt = 0; dt < 2; ++dt)
      #pragma unroll
      for (int s = 0; s < 2; ++s) vf[dt][s] = vn[dt][s];
  }
  // epilogue: lane l holds O^T[d][q=lane&31]; d = dt*32 + 8*rq + 4*h + (0..3)
  int b = bh >> 4, hh = bh & 15;
  float inv = 1.0f / lS;
  unsigned short* outp = AO + ((size_t)(b * SEQ + q0 + lr)) * EMB + hh * HD;
  #pragma unroll
  for (int dt = 0; dt < 2; ++dt){
    #pragma unroll
    for (int rq = 0; rq < 4; ++rq){
      float v0 = (dt ? ot1 : ot0)[rq * 4 + 0] * inv;
      float v1 = (dt ? ot1 : ot0)[rq * 4 + 1] * inv;
      float v2 = (dt ? ot1 : ot0)[rq * 4 + 2] * inv;
      float v3 = (dt ? ot1 : ot0)[rq * 4 + 3] * inv;
      uint2 wv;
      wv.x = cvtpk(v0, v1);
      wv.y = cvtpk(v2, v3);
      int d0 = dt * 32 + 8 * rq + 4 * h;
      *(uint2*)(outp + d0) = wv;
    }
  }
}

extern "C" void kernel_launch(void* const* d_in, const int* in_sizes, int n_in,
                              void* d_out, int out_size, void* d_ws, size_t ws_size,
                              hipStream_t stream){
  const float* x  = (const float*)d_in[0];
  const float* Wq = (const float*)d_in[2];
  const float* Wk = (const float*)d_in[3];
  const float* Wv = (const float*)d_in[4];
  const float* Wo = (const float*)d_in[5];
  float* out = (float*)d_out;

  char* ws = (char*)d_ws;
  size_t off = 0;
  auto alloc = [&](size_t bytes){ void* p = ws + off; off += (bytes + 255) & ~(size_t)255; return p; };
  unsigned short* xb    = (unsigned short*)alloc((size_t)4096 * 1024 * 2);
  unsigned short* wto   = (unsigned short*)alloc((size_t)1024 * 1024 * 2);
  unsigned short* qb    = (unsigned short*)alloc((size_t)4096 * 1024 * 2);
  unsigned short* kb    = (unsigned short*)alloc((size_t)4096 * 1024 * 2);
  unsigned short* vb    = (unsigned short*)alloc((size_t)4096 * 1024 * 2);
  float2*         tb    = (float2*)alloc((size_t)2048 * 32 * 8);
  unsigned short* wtqkv = (unsigned short*)alloc((size_t)4096 * 1024 * 2);  // 8MB region: wtqkv(6MB) then reused as Kf(8MB)
  unsigned short* Qf = xb;     // xb dead after k_gemm<0>
  unsigned short* Kf = wtqkv;  // wtqkv dead after k_gemm<0>
  unsigned short* Vf = qb;     // qb dead after k_rope_frag
  unsigned short* ao = kb;     // kb dead after k_rope_frag

  k_convert<<<dim3(2048), dim3(256), 0, stream>>>(x, xb, 524288);
  k_transpose_w<<<dim3(32, 32, 4), dim3(32, 8), 0, stream>>>(Wq, Wk, Wv, Wo, wtqkv, wto);
  k_rope_table<<<dim3(256), dim3(256), 0, stream>>>(tb);
  k_gemm<0><<<dim3(32, 24), dim3(256), 0, stream>>>(xb, wtqkv, qb, kb, vb, nullptr);
  k_rope_frag<<<dim3(64, 32, 2), dim3(64), 0, stream>>>(qb, kb, Qf, Kf, tb);
  k_vfrag<<<dim3(64, 32), dim3(64), 0, stream>>>(vb, Vf);
  k_attn<<<dim3(2048), dim3(64), 0, stream>>>(Qf, Kf, Vf, ao);
  k_gemm<1><<<dim3(32, 8), dim3(256), 0, stream>>>(ao, wto, nullptr, nullptr, nullptr, out);
}